// Round 13
// baseline (192.773 us; speedup 1.0000x reference)
//
#include <hip/hip_runtime.h>
#include <stdint.h>

#define B_ 8
#define C_ 256
#define H_ 96
#define W_ 160
#define ND 9
#define NDISP 81
#define CK 2                   // channels per chunk
#define NCHUNK (C_ / CK)       // 128
#define TX 4
#define NXG 20                 // x-groups per half (half-width 80 = 20*4)
#define NTHR 64                // ONE wave per block, no barriers
#define NCOMP 60               // 3 dyl * 20 xg
// LDS chunk layout: 6 rows (2 ch x 3 dyl) of in2 only; in1 is global->reg.
// ROW_B=352 (22*16B): dyl groups start at banks {0,24,16} -> per-octant
// bank load 8/7/7/8 (ideal 7.5) -> near-min-phase w-reads, no swizzle.
// INVARIANT: row stride multiple of 16B DMA width (R8 lesson).
#define ROW_B 352              // 88 floats: global x [80h-4, 80h+84)
#define CHUNK_B 2112           // 6 * 352
#define BUF_B 3072             // 3 x 1024B DMA slots; %512 == 0
#define BUF_F 768
#define NBUF 2
#define HW (H_ * W_)
#define CHSTEP (CK * HW)       // global float step per chunk

typedef const __attribute__((address_space(1))) void GV;
typedef __attribute__((address_space(3))) void LV;
#define DMA16(g, l) __builtin_amdgcn_global_load_lds((GV*)(g), (LV*)(l), 16, 0, 0)

// Map physical LDS byte offset O (linear) to its in2 source. Clamped
// positions hold finite garbage that is masked in FMA / scaled by 0.
__device__ __forceinline__ const float* decode_src(int O, int b, int y,
        int dyg, int h, const float* in1, const float* in2)
{
    if (O >= CHUNK_B) return in1;          // slot-2 tail dummy (never read)
    const int R  = O / ROW_B;              // 0..5
    const int fb = O - R * ROW_B;
    const int ch = R / 3;
    const int dyl = R - ch * 3;
    int row = y + dyg * 3 + dyl - 4;
    row = row < 0 ? 0 : (row >= H_ ? H_ - 1 : row);      // clamp; masked later
    int x = 80 * h - 4 + (fb >> 2);
    x = x < 0 ? 0 : (x > W_ - TX ? W_ - TX : x);         // clamp; masked later
    return in2 + ((size_t)(b * C_ + ch) * H_ + row) * W_ + x;  // 16B-aligned
}

__global__ __launch_bounds__(NTHR) void corr_g1_kernel(
    const float* __restrict__ in1,
    const float* __restrict__ in2,
    float* __restrict__ out)
{
    __shared__ float lds[NBUF * BUF_F];   // 6144 B, never zero-inited

    const int tid = threadIdx.x;
    const int b   = blockIdx.x & 7;       // XCD swizzle: batch pinned to XCD
    const int idx = blockIdx.x >> 3;      // 0..575
    const int y   = idx / 6;
    const int t6  = idx % 6;
    const int dyg = t6 >> 1;              // 0..2 (dy = dyg*3 + dyl)
    const int h   = t6 & 1;               // x half

    // ---- per-lane DMA sources: 3 slots
    const float* g0 = decode_src(0 * 1024 + tid * 16, b, y, dyg, h, in1, in2);
    const float* g1 = decode_src(1 * 1024 + tid * 16, b, y, dyg, h, in1, in2);
    const float* g2 = decode_src(2 * 1024 + tid * 16, b, y, dyg, h, in1, in2);

    // ---- compute coords; lanes 60-63 clamp onto lanes 0-3 (same-addr
    // broadcast = free; their acc is never stored)
    const bool isComp = (tid < NCOMP);
    const int  dyl = isComp ? (tid / NXG) : 0;
    const int  xg  = isComp ? (tid % NXG) : (tid - NCOMP);   // 0..19 / 0..3
    const int  x0  = 80 * h + TX * xg;
    const int  dy  = dyg * 3 + dyl;       // 0..8
    const bool rowOk = (y + dy - 4 >= 0) && (y + dy - 4 < H_);
    const bool mzW0 = (h == 0) && (xg == 0);        // w0 = x [-4,0): zero-pad
    const bool mzW2 = (h == 1) && (xg == NXG - 1);  // w2 = x [160,164)

    // ---- w-read offsets (bytes, buffer-local, linear)
    const int wb0 = (0 + dyl) * ROW_B + 16 * xg;    // ch0 row, f = 4xg
    const int wb1 = (3 + dyl) * ROW_B + 16 * xg;    // ch1 row

    // ---- in1 direct-global pointer (lane-private x window, L1/L2-served)
    const float* ap = in1 + ((size_t)(b * C_) * H_ + y) * W_ + x0;

    float acc[ND][TX];
    #pragma unroll
    for (int dx = 0; dx < ND; ++dx)
        #pragma unroll
        for (int j = 0; j < TX; ++j) acc[dx][j] = 0.f;

    float4 raC0, raC1, rbC0, rbC1;        // a-staging, static 2-set alternation

    #define ISSUE(BUFI) do {                                                  \
        float* lb = &lds[(BUFI) * BUF_F];                                     \
        DMA16(g0, lb);                                                        \
        DMA16(g1, lb + 256);                                                  \
        DMA16(g2, lb + 512);                                                  \
        g0 += CHSTEP; g1 += CHSTEP; g2 += CHSTEP;                             \
    } while (0);

    #define LOADA(RC0, RC1) do {                                              \
        RC0 = *(const float4*)(ap);                                           \
        RC1 = *(const float4*)(ap + HW);                                      \
        ap += CHSTEP;                                                         \
    } while (0);

    #define FMACH(A4, WB) {                                                   \
        float4 w0 = *(const float4*)(bb + (WB));                              \
        float4 w1 = *(const float4*)(bb + (WB) + 16);                         \
        float4 w2 = *(const float4*)(bb + (WB) + 32);                         \
        if (mzW0) w0 = make_float4(0.f, 0.f, 0.f, 0.f);                       \
        if (mzW2) w2 = make_float4(0.f, 0.f, 0.f, 0.f);                       \
        float a[4]  = {(A4).x, (A4).y, (A4).z, (A4).w};                       \
        float w[12] = {w0.x, w0.y, w0.z, w0.w, w1.x, w1.y, w1.z, w1.w,        \
                       w2.x, w2.y, w2.z, w2.w};                               \
        _Pragma("unroll")                                                     \
        for (int dx = 0; dx < ND; ++dx) {                                     \
            _Pragma("unroll")                                                 \
            for (int j = 0; j < TX; ++j)                                      \
                acc[dx][j] += a[j] * w[dx + j];                               \
        }                                                                     \
    }

    #define COMPUTE(BUFI, RC0, RC1) {                                         \
        const char* bb = (const char*)lds + (BUFI) * BUF_B;                   \
        FMACH(RC0, wb0)                                                       \
        FMACH(RC1, wb1)                                                       \
    }

    // body kc (wave-local, NO barrier). Steady-state entry queue (oldest
    // first): [DMA kc (3), a kc (2), DMA kc+1 (3)] -> vmcnt(3) completes
    // chunk kc's DMA AND its a-loads, leaves DMA kc+1 in flight.
    #define BODY(BUFI, WN, DOA, DOD, RC0, RC1, RN0, RN1)                      \
        asm volatile("s_waitcnt vmcnt(" WN ")" ::: "memory");                 \
        __builtin_amdgcn_sched_barrier(0);                                    \
        if (DOA) { LOADA(RN0, RN1) }                                          \
        COMPUTE(BUFI, RC0, RC1)                                               \
        asm volatile("s_waitcnt lgkmcnt(0)" ::: "memory");                    \
        __builtin_amdgcn_sched_barrier(0);                                    \
        if (DOD) { ISSUE(BUFI) }

    // ---- prologue: order DMA0, a0, DMA1 -> queue [3,2,3]
    ISSUE(0)
    LOADA(raC0, raC1)
    ISSUE(1)

    // ---- main loop: kc = 0..125
    #pragma unroll 1
    for (int g = 0; g < 63; ++g) {
        BODY(0, "3", true, true, raC0, raC1, rbC0, rbC1)
        BODY(1, "3", true, true, rbC0, rbC1, raC0, raC1)
    }
    // ---- tail: kc = 126 (issues a127 only), kc = 127
    BODY(0, "3", true,  false, raC0, raC1, rbC0, rbC1)
    BODY(1, "0", false, false, rbC0, rbC1, raC0, raC1)

    #undef BODY
    #undef COMPUTE
    #undef FMACH
    #undef LOADA
    #undef ISSUE

    // ---- epilogue: OOB-dy rows output zeros (masked scale; staged clamped
    // garbage is finite real data, so 0-scale is exact)
    if (isComp) {
        const float m = rowOk ? (1.0f / (float)C_) : 0.f;
        float* outp = out + ((size_t)(b * NDISP + dy * ND) * H_ + y) * W_ + x0;
        #pragma unroll
        for (int dx = 0; dx < ND; ++dx) {
            float4 o = make_float4(acc[dx][0] * m, acc[dx][1] * m,
                                   acc[dx][2] * m, acc[dx][3] * m);
            *(float4*)(outp + dx * HW) = o;
        }
    }
}

extern "C" void kernel_launch(void* const* d_in, const int* in_sizes, int n_in,
                              void* d_out, int out_size, void* d_ws, size_t ws_size,
                              hipStream_t stream) {
    const float* in1 = (const float*)d_in[0];
    const float* in2 = (const float*)d_in[1];
    float* out = (float*)d_out;

    const int grid = B_ * H_ * 3 * 2;   // 4608 single-wave blocks (~18/CU)
    corr_g1_kernel<<<grid, NTHR, 0, stream>>>(in1, in2, out);
}

// Round 14
// 174.502 us; speedup vs baseline: 1.1047x; 1.1047x over previous
//
#include <hip/hip_runtime.h>
#include <stdint.h>

#define B_ 8
#define C_ 256
#define H_ 96
#define W_ 160
#define ND 9
#define NDISP 81
#define NCHUNK 128             // channels per wave (2-way interleaved ch split)
#define TX 8
#define NXG 20
#define NTHR 128               // 2 independent waves; NO main-loop barrier
#define NCOMP 60               // 3 dyl * 20 xg per wave
// Per-wave chunk layout (bytes): in1 row @0 (640 B = 160 f);
// in2 row dyl r @ 640 + 688*r (172-float slot, 168 real: x in [-4,164)).
// INVARIANT: all row offsets/strides are multiples of the 16B DMA width (R8).
#define IN2_OFF 640
#define ROW_B 688              // 43*16
#define CHUNK_B 2704
#define BUF_B 3072             // 3 x 1024B DMA slots
#define NBUF 2
#define WAVE_LDS (NBUF * BUF_B)   // 6144 B per wave; block total 12288
#define HW (H_ * W_)
#define CHSTEP (2 * HW)        // channel += 2 per chunk

typedef const __attribute__((address_space(1))) void GV;
typedef __attribute__((address_space(3))) void LV;
#define DMA16(g, l) __builtin_amdgcn_global_load_lds((GV*)(g), (LV*)(l), 16, 0, 0)

// Map physical per-wave LDS byte offset O (linear, no swizzle) to the global
// source for channel ch. Clamped positions hold finite garbage, masked later.
__device__ __forceinline__ const float* decode_src(int O, int b, int y,
        int dyg, int ch, const float* in1, const float* in2)
{
    if (O >= CHUNK_B) return in1;          // slot-2 tail dummy (never read)
    if (O < IN2_OFF) {                     // in1 row y, x = O/4 in [0,160)
        return in1 + ((size_t)(b * C_ + ch) * H_ + y) * W_ + (O >> 2);
    }
    const int rem = O - IN2_OFF;
    const int r   = rem / ROW_B;           // dyl 0..2
    const int fb  = rem - r * ROW_B;
    int row = y + dyg * 3 + r - 4;
    row = row < 0 ? 0 : (row >= H_ ? H_ - 1 : row);      // clamp; masked later
    int x = (fb < 672) ? ((fb >> 2) - 4) : 0;            // row pad -> dummy
    x = x < 0 ? 0 : (x > W_ - 4 ? W_ - 4 : x);           // clamp; masked later
    return in2 + ((size_t)(b * C_ + ch) * H_ + row) * W_ + x;  // 16B-aligned
}

__global__ __launch_bounds__(NTHR) void corr_cw_kernel(
    const float* __restrict__ in1,
    const float* __restrict__ in2,
    float* __restrict__ out)
{
    __shared__ float lds[2 * WAVE_LDS / 4];   // 12288 B, never zero-inited

    const int tid  = threadIdx.x;
    const int wv   = tid >> 6;            // 0/1: channel-parity wave
    const int lane = tid & 63;
    const int b    = blockIdx.x & 7;      // XCD swizzle: batch pinned to XCD
    const int idx  = blockIdx.x >> 3;     // 0..287
    const int y    = idx / 3;
    const int dyg  = idx % 3;             // dy = dyg*3 + dyl

    // ---- per-lane DMA sources: 3 slots, channel base = wv
    const float* g0 = decode_src(0 * 1024 + lane * 16, b, y, dyg, wv, in1, in2);
    const float* g1 = decode_src(1 * 1024 + lane * 16, b, y, dyg, wv, in1, in2);
    const float* g2 = decode_src(2 * 1024 + lane * 16, b, y, dyg, wv, in1, in2);

    // ---- compute coords (lanes 0-59): dyl-major; 60-63 clamp onto 0-3
    const bool isComp = (lane < NCOMP);
    const int  dyl = isComp ? (lane / NXG) : 0;
    const int  xg  = isComp ? (lane % NXG) : (lane - NCOMP);
    const int  x0  = TX * xg;
    const int  dy  = dyg * 3 + dyl;       // 0..8
    const bool rowOk = (y + dy - 4 >= 0) && (y + dy - 4 < H_);
    const bool mzW0 = (xg == 0);          // w0 = x [-4,0): zero-pad
    const bool mzW3 = (xg == NXG - 1);    // w3 = x [160,164)

    // ---- read offsets (bytes, wave-buffer-local, linear)
    const int aof  = 32 * xg;                      // in1: 2 reads @aof, aof+16
    const int wb   = IN2_OFF + dyl * ROW_B + 32 * xg;  // in2: 4 reads

    char* const wbase = (char*)lds + wv * WAVE_LDS;

    float acc[ND][TX];
    #pragma unroll
    for (int dx = 0; dx < ND; ++dx)
        #pragma unroll
        for (int j = 0; j < TX; ++j) acc[dx][j] = 0.f;

    #define ISSUE(BUFI) do {                                                  \
        char* lb = wbase + (BUFI) * BUF_B;                                    \
        DMA16(g0, lb);                                                        \
        DMA16(g1, lb + 1024);                                                 \
        DMA16(g2, lb + 2048);                                                 \
        g0 += CHSTEP; g1 += CHSTEP; g2 += CHSTEP;                             \
    } while (0);

    #define COMPUTE(BUFI)                                                     \
    {                                                                         \
        const char* bb = wbase + (BUFI) * BUF_B;                              \
        float4 a0 = *(const float4*)(bb + aof);                               \
        float4 a1 = *(const float4*)(bb + aof + 16);                          \
        float4 w0 = *(const float4*)(bb + wb);                                \
        float4 w1 = *(const float4*)(bb + wb + 16);                           \
        float4 w2 = *(const float4*)(bb + wb + 32);                           \
        float4 w3 = *(const float4*)(bb + wb + 48);                           \
        if (mzW0) w0 = make_float4(0.f, 0.f, 0.f, 0.f);                       \
        if (mzW3) w3 = make_float4(0.f, 0.f, 0.f, 0.f);                       \
        float a[8]  = {a0.x, a0.y, a0.z, a0.w, a1.x, a1.y, a1.z, a1.w};       \
        float w[16] = {w0.x, w0.y, w0.z, w0.w, w1.x, w1.y, w1.z, w1.w,        \
                       w2.x, w2.y, w2.z, w2.w, w3.x, w3.y, w3.z, w3.w};       \
        _Pragma("unroll")                                                     \
        for (int dx = 0; dx < ND; ++dx) {                                     \
            _Pragma("unroll")                                                 \
            for (int j = 0; j < TX; ++j)                                      \
                acc[dx][j] += a[j] * w[dx + j];                               \
        }                                                                     \
    }

    // body kc (wave-local): vmcnt(3) = chunk kc's 3 DMAs landed (kc+1's 3
    // outstanding); COMPUTE; lgkmcnt(0) = own reads retired -> overwrite ok.
    #define BODY(BUFI, WN, DOISS)                                             \
        asm volatile("s_waitcnt vmcnt(" WN ")" ::: "memory");                 \
        __builtin_amdgcn_sched_barrier(0);                                    \
        COMPUTE(BUFI)                                                         \
        asm volatile("s_waitcnt lgkmcnt(0)" ::: "memory");                    \
        __builtin_amdgcn_sched_barrier(0);                                    \
        if (DOISS) { ISSUE(BUFI) }

    // ---- prologue
    ISSUE(0)
    ISSUE(1)

    // ---- main loop: kc = 0..125
    #pragma unroll 1
    for (int g = 0; g < 63; ++g) {
        BODY(0, "3", true)
        BODY(1, "3", true)
    }
    // ---- tail: kc = 126, 127
    BODY(0, "3", false)
    BODY(1, "0", false)

    #undef BODY
    #undef COMPUTE
    #undef ISSUE

    // ---- cross-wave reduction: wave1's partial accs added into wave0's.
    // Both waves' main loops drained (lgkmcnt(0)/vmcnt(0) in tails).
    float* red = (float*)lds;
    const int rl = dyl * NXG + xg;        // 0..59
    __syncthreads();
    if (wv == 1 && isComp) {              // batch 0: dx 0..3 (32 f/lane, 7.7KB)
        #pragma unroll
        for (int dx = 0; dx < 4; ++dx) {
            *(float4*)(red + rl * 32 + dx * 8)     =
                make_float4(acc[dx][0], acc[dx][1], acc[dx][2], acc[dx][3]);
            *(float4*)(red + rl * 32 + dx * 8 + 4) =
                make_float4(acc[dx][4], acc[dx][5], acc[dx][6], acc[dx][7]);
        }
    }
    __syncthreads();
    if (wv == 0 && isComp) {
        #pragma unroll
        for (int dx = 0; dx < 4; ++dx)
            #pragma unroll
            for (int j = 0; j < TX; ++j)
                acc[dx][j] += red[rl * 32 + dx * 8 + j];
    }
    __syncthreads();
    if (wv == 1 && isComp) {              // batch 1: dx 4..8 (40 f/lane, 9.6KB)
        #pragma unroll
        for (int dx = 4; dx < ND; ++dx) {
            *(float4*)(red + rl * 40 + (dx - 4) * 8)     =
                make_float4(acc[dx][0], acc[dx][1], acc[dx][2], acc[dx][3]);
            *(float4*)(red + rl * 40 + (dx - 4) * 8 + 4) =
                make_float4(acc[dx][4], acc[dx][5], acc[dx][6], acc[dx][7]);
        }
    }
    __syncthreads();
    if (wv == 0 && isComp) {
        #pragma unroll
        for (int dx = 4; dx < ND; ++dx)
            #pragma unroll
            for (int j = 0; j < TX; ++j)
                acc[dx][j] += red[rl * 40 + (dx - 4) * 8 + j];

        // ---- store (OOB-dy rows output zeros via masked scale)
        const float m = rowOk ? (1.0f / (float)C_) : 0.f;
        float* outp = out + ((size_t)(b * NDISP + dy * ND) * H_ + y) * W_ + x0;
        #pragma unroll
        for (int dx = 0; dx < ND; ++dx) {
            float4 o0 = make_float4(acc[dx][0] * m, acc[dx][1] * m,
                                    acc[dx][2] * m, acc[dx][3] * m);
            float4 o1 = make_float4(acc[dx][4] * m, acc[dx][5] * m,
                                    acc[dx][6] * m, acc[dx][7] * m);
            *(float4*)(outp + dx * HW)     = o0;
            *(float4*)(outp + dx * HW + 4) = o1;
        }
    }
}

extern "C" void kernel_launch(void* const* d_in, const int* in_sizes, int n_in,
                              void* d_out, int out_size, void* d_ws, size_t ws_size,
                              hipStream_t stream) {
    const float* in1 = (const float*)d_in[0];
    const float* in2 = (const float*)d_in[1];
    float* out = (float*)d_out;

    const int grid = B_ * H_ * 3;   // 2304 blocks x 2 waves = 18 waves/CU
    corr_cw_kernel<<<grid, NTHR, 0, stream>>>(in1, in2, out);
}